// Round 2
// baseline (9800.437 us; speedup 1.0000x reference)
//
#include <hip/hip_runtime.h>
#include <hip/hip_bf16.h>
#include <math.h>

typedef __hip_bfloat16 bf16;

__device__ __forceinline__ float bf2f(unsigned short u) {
    unsigned int w = ((unsigned int)u) << 16;
    float f;
    __builtin_memcpy(&f, &w, 4);
    return f;
}

// flag: 1 = inputs are fp32, 0 = inputs are bf16
__device__ __forceinline__ float ldIn(const void* p, size_t i, int f) {
    return f ? ((const float*)p)[i] : bf2f(((const unsigned short*)p)[i]);
}

// ---------------------------------------------------------------------------
// dtype detector: scan first n uint16s of W0. bf16 weights (~N(0,0.02)) have
// exponent field <= ~124; fp32 data's low halves are quasi-random -> ~11% of
// scanned uint16s have exp >= 0xC5. Writes flag = (count > 1000).
// ---------------------------------------------------------------------------
__global__ __launch_bounds__(256) void detect_kernel(
    const unsigned short* __restrict__ w, int n, int* __restrict__ flag)
{
    __shared__ int red[256];
    int cnt = 0;
    for (int i = threadIdx.x; i < n; i += 256) {
        unsigned int e = (w[i] >> 7) & 0xFF;
        cnt += (e >= 0xC5) ? 1 : 0;
    }
    red[threadIdx.x] = cnt;
    __syncthreads();
    for (int s = 128; s > 0; s >>= 1) {
        if (threadIdx.x < s) red[threadIdx.x] += red[threadIdx.x + s];
        __syncthreads();
    }
    if (threadIdx.x == 0) flag[0] = (red[0] > 1000) ? 1 : 0;
}

// ---------------------------------------------------------------------------
// Tiled fp32 GEMM: C[M,N] = A[M,K] @ B[K,N] + bias[N]
// AWS: A is fp32 workspace. Otherwise A dtype per flag. B/bias dtype per flag.
// 64x64 tile, BK=16, 256 threads, 4x4 micro-tile per thread.
// ---------------------------------------------------------------------------
template <bool AWS>
__global__ __launch_bounds__(256) void gemm_kernel(
    const void* __restrict__ A, const void* __restrict__ B,
    const void* __restrict__ bias, float* __restrict__ C,
    int M, int N, int K, const int* __restrict__ flag)
{
    const int f = flag[0];
    __shared__ __align__(16) float As[16][68];
    __shared__ __align__(16) float Bs[16][68];

    const int tid = threadIdx.x;
    const int bm = blockIdx.y * 64;
    const int bn = blockIdx.x * 64;
    const int tx = tid & 15;
    const int ty = tid >> 4;

    const int ar = tid >> 2;          // A-tile row 0..63
    const int ak = (tid & 3) << 2;    // A-tile k 0,4,8,12
    const int br = tid >> 4;          // B-tile k-row 0..15
    const int bc = (tid & 15) << 2;   // B-tile col 0..60

    float acc[4][4] = {};

    for (int k0 = 0; k0 < K; k0 += 16) {
#pragma unroll
        for (int i = 0; i < 4; i++) {
            int kg = k0 + ak + i;
            size_t idx = (size_t)(bm + ar) * K + kg;
            float v = 0.f;
            if (kg < K) v = AWS ? ((const float*)A)[idx] : ldIn(A, idx, f);
            As[ak + i][ar] = v;
        }
#pragma unroll
        for (int j = 0; j < 4; j++) {
            int kg = k0 + br;
            int col = bn + bc + j;
            float v = 0.f;
            if (kg < K && col < N) v = ldIn(B, (size_t)kg * N + col, f);
            Bs[br][bc + j] = v;
        }
        __syncthreads();

#pragma unroll
        for (int k = 0; k < 16; k++) {
            float4 av = *(const float4*)&As[k][ty * 4];
            float4 bv = *(const float4*)&Bs[k][tx * 4];
            float a[4] = {av.x, av.y, av.z, av.w};
            float b[4] = {bv.x, bv.y, bv.z, bv.w};
#pragma unroll
            for (int i = 0; i < 4; i++)
#pragma unroll
                for (int j = 0; j < 4; j++)
                    acc[i][j] += a[i] * b[j];
        }
        __syncthreads();
    }

#pragma unroll
    for (int i = 0; i < 4; i++) {
        int row = bm + ty * 4 + i;
#pragma unroll
        for (int j = 0; j < 4; j++) {
            int col = bn + tx * 4 + j;
            if (col < N)
                C[(size_t)row * N + col] = acc[i][j] + ldIn(bias, col, f);
        }
    }
}

// ---------------------------------------------------------------------------
__global__ __launch_bounds__(256) void colstats_kernel(
    const float* __restrict__ Y, float* __restrict__ part, int N, int rows)
{
    int c = blockIdx.x * 256 + threadIdx.x;
    int r0 = blockIdx.y * rows;
    const float* p = Y + (size_t)r0 * N + c;
    float s = 0.f, s2 = 0.f;
    for (int r = 0; r < rows; r++) {
        float v = p[(size_t)r * N];
        s += v;
        s2 += v * v;
    }
    part[(size_t)(blockIdx.y * 2 + 0) * N + c] = s;
    part[(size_t)(blockIdx.y * 2 + 1) * N + c] = s2;
}

__global__ void finalize_stats_kernel(
    const float* __restrict__ part, const void* __restrict__ g,
    const void* __restrict__ be, float* __restrict__ scale,
    float* __restrict__ shift, int N, int nchunk, float invM,
    const int* __restrict__ flag)
{
    const int f = flag[0];
    int c = blockIdx.x * blockDim.x + threadIdx.x;
    if (c >= N) return;
    float s = 0.f, s2 = 0.f;
    for (int i = 0; i < nchunk; i++) {
        s  += part[(size_t)(2 * i + 0) * N + c];
        s2 += part[(size_t)(2 * i + 1) * N + c];
    }
    float m = s * invM;
    float v = s2 * invM - m * m;
    if (v < 0.f) v = 0.f;
    float sc = ldIn(g, c, f) / sqrtf(v + 1e-5f);
    scale[c] = sc;
    shift[c] = ldIn(be, c, f) - m * sc;
}

__global__ __launch_bounds__(256) void bn_apply_kernel(
    float* __restrict__ Y, const float* __restrict__ scale,
    const float* __restrict__ shift, int do_relu, int n4, int N)
{
    int idx = blockIdx.x * 256 + threadIdx.x;
    if (idx >= n4) return;
    float4* Y4 = (float4*)Y;
    float4 v = Y4[idx];
    int c = (idx * 4) & (N - 1);
    v.x = v.x * scale[c + 0] + shift[c + 0];
    v.y = v.y * scale[c + 1] + shift[c + 1];
    v.z = v.z * scale[c + 2] + shift[c + 2];
    v.w = v.w * scale[c + 3] + shift[c + 3];
    if (do_relu) {
        v.x = fmaxf(v.x, 0.f); v.y = fmaxf(v.y, 0.f);
        v.z = fmaxf(v.z, 0.f); v.w = fmaxf(v.w, 0.f);
    }
    Y4[idx] = v;
}

__global__ __launch_bounds__(256) void resid_relu_kernel(
    float* __restrict__ H, const float* __restrict__ T, int n4)
{
    int idx = blockIdx.x * 256 + threadIdx.x;
    if (idx >= n4) return;
    float4 h = ((float4*)H)[idx];
    float4 t = ((const float4*)T)[idx];
    h.x = fmaxf(h.x + t.x, 0.f);
    h.y = fmaxf(h.y + t.y, 0.f);
    h.z = fmaxf(h.z + t.z, 0.f);
    h.w = fmaxf(h.w + t.w, 0.f);
    ((float4*)H)[idx] = h;
}

// ---------------------------------------------------------------------------
// O = det(R)*R, R = polar(M). Jacobi eigensolver on M^T M in fp64.
// Output dtype follows detected input dtype (flag).
// ---------------------------------------------------------------------------
__global__ __launch_bounds__(256) void svd_kernel(
    const float* __restrict__ O3, void* __restrict__ out,
    int nb, const int* __restrict__ flag)
{
    const int f = flag[0];
    int gidx = blockIdx.x * 256 + threadIdx.x;
    if (gidx >= nb * 24) return;
    int row = gidx / 24;
    int j = gidx - row * 24;
    const float* rowp = O3 + (size_t)row * 226;
    const float* src = rowp + j * 9;

    double m[3][3];
#pragma unroll
    for (int r = 0; r < 3; r++)
#pragma unroll
        for (int c = 0; c < 3; c++) m[r][c] = (double)src[r * 3 + c];

    double a[3][3];
#pragma unroll
    for (int r = 0; r < 3; r++)
#pragma unroll
        for (int c = 0; c < 3; c++) {
            double s = 0.0;
#pragma unroll
            for (int k = 0; k < 3; k++) s += m[k][r] * m[k][c];
            a[r][c] = s;
        }

    double V[3][3] = {{1, 0, 0}, {0, 1, 0}, {0, 0, 1}};
    const int PP[3] = {0, 0, 1}, QQ[3] = {1, 2, 2};
    for (int sweep = 0; sweep < 8; sweep++) {
        for (int r3 = 0; r3 < 3; r3++) {
            int p = PP[r3], q = QQ[r3];
            double apq = a[p][q];
            if (fabs(apq) < 1e-60) continue;
            double tau = (a[q][q] - a[p][p]) / (2.0 * apq);
            double t = ((tau >= 0.0) ? 1.0 : -1.0) / (fabs(tau) + sqrt(1.0 + tau * tau));
            double c = 1.0 / sqrt(1.0 + t * t);
            double s = t * c;
#pragma unroll
            for (int k = 0; k < 3; k++) {
                double xp = a[p][k], xq = a[q][k];
                a[p][k] = c * xp - s * xq;
                a[q][k] = s * xp + c * xq;
            }
#pragma unroll
            for (int k = 0; k < 3; k++) {
                double xp = a[k][p], xq = a[k][q];
                a[k][p] = c * xp - s * xq;
                a[k][q] = s * xp + c * xq;
            }
#pragma unroll
            for (int k = 0; k < 3; k++) {
                double xp = V[k][p], xq = V[k][q];
                V[k][p] = c * xp - s * xq;
                V[k][q] = s * xp + c * xq;
            }
        }
    }

    double lam[3] = {a[0][0], a[1][1], a[2][2]};
    int i3 = 0;
    if (lam[1] < lam[i3]) i3 = 1;
    if (lam[2] < lam[i3]) i3 = 2;
    int i1 = (i3 + 1) % 3, i2 = (i3 + 2) % 3;

    double v1[3], v2[3], v3[3];
#pragma unroll
    for (int k = 0; k < 3; k++) {
        v1[k] = V[k][i1];
        v2[k] = V[k][i2];
        v3[k] = V[k][i3];
    }

    double u1[3], u2[3];
#pragma unroll
    for (int r = 0; r < 3; r++)
        u1[r] = m[r][0] * v1[0] + m[r][1] * v1[1] + m[r][2] * v1[2];
    double n1 = sqrt(u1[0] * u1[0] + u1[1] * u1[1] + u1[2] * u1[2]);
    double inv1 = (n1 > 1e-150) ? 1.0 / n1 : 0.0;
#pragma unroll
    for (int r = 0; r < 3; r++) u1[r] *= inv1;

#pragma unroll
    for (int r = 0; r < 3; r++)
        u2[r] = m[r][0] * v2[0] + m[r][1] * v2[1] + m[r][2] * v2[2];
    double d12 = u1[0] * u2[0] + u1[1] * u2[1] + u1[2] * u2[2];
#pragma unroll
    for (int r = 0; r < 3; r++) u2[r] -= d12 * u1[r];
    double n2 = sqrt(u2[0] * u2[0] + u2[1] * u2[1] + u2[2] * u2[2]);
    double inv2 = (n2 > 1e-150) ? 1.0 / n2 : 0.0;
#pragma unroll
    for (int r = 0; r < 3; r++) u2[r] *= inv2;

    double detM = m[0][0] * (m[1][1] * m[2][2] - m[1][2] * m[2][1])
                - m[0][1] * (m[1][0] * m[2][2] - m[1][2] * m[2][0])
                + m[0][2] * (m[1][0] * m[2][1] - m[1][1] * m[2][0]);
    double sgn = (detM >= 0.0) ? 1.0 : -1.0;
    double detV = v1[0] * (v2[1] * v3[2] - v2[2] * v3[1])
                - v1[1] * (v2[0] * v3[2] - v2[2] * v3[0])
                + v1[2] * (v2[0] * v3[1] - v2[1] * v3[0]);
    double sv = (detV >= 0.0) ? 1.0 : -1.0;

    double u3[3];
    u3[0] = sgn * sv * (u1[1] * u2[2] - u1[2] * u2[1]);
    u3[1] = sgn * sv * (u1[2] * u2[0] - u1[0] * u2[2]);
    u3[2] = sgn * sv * (u1[0] * u2[1] - u1[1] * u2[0]);

    // rotmat then betas, dtype per flag
    size_t rot_base = (size_t)gidx * 9;
    size_t beta_base = (size_t)196608 * 9 + (size_t)row * 10;  // nb*24*9
#pragma unroll
    for (int r = 0; r < 3; r++)
#pragma unroll
        for (int c = 0; c < 3; c++) {
            float o = (float)(sgn * (u1[r] * v1[c] + u2[r] * v2[c] + u3[r] * v3[c]));
            if (f) ((float*)out)[rot_base + r * 3 + c] = o;
            else   ((bf16*)out)[rot_base + r * 3 + c] = __float2bfloat16(o);
        }

    if (j < 10) {
        float b = rowp[216 + j];
        if (f) ((float*)out)[beta_base + j] = b;
        else   ((bf16*)out)[beta_base + j] = __float2bfloat16(b);
    }
}

// ---------------------------------------------------------------------------
extern "C" void kernel_launch(void* const* d_in, const int* in_sizes, int n_in,
                              void* d_out, int out_size, void* d_ws, size_t ws_size,
                              hipStream_t stream)
{
    const void* x    = d_in[0];
    const void* W0   = d_in[1];
    const void* b0   = d_in[2];
    const void* g0   = d_in[3];
    const void* be0  = d_in[4];
    const void* W1a  = d_in[5];
    const void* b1a  = d_in[6];
    const void* g1a  = d_in[7];
    const void* be1a = d_in[8];
    const void* W1b  = d_in[9];
    const void* b1b  = d_in[10];
    const void* g1b  = d_in[11];
    const void* be1b = d_in[12];
    const void* W2a  = d_in[13];
    const void* b2a  = d_in[14];
    const void* g2a  = d_in[15];
    const void* be2a = d_in[16];
    const void* W2b  = d_in[17];
    const void* b2b  = d_in[18];
    const void* g2b  = d_in[19];
    const void* be2b = d_in[20];
    const void* W3   = d_in[21];
    const void* b3   = d_in[22];

    const int M = 8192, H = 1024, K0 = 5169, NO = 226;
    const int NCHUNK = 32;

    float* ws   = (float*)d_ws;
    float* buf0 = ws;                          // 8192*1024 : h
    float* buf1 = buf0 + (size_t)M * H;        // 8192*1024 : t
    float* buf2 = buf1 + (size_t)M * H;        // 8192*1024 : t2
    float* buf3 = buf2 + (size_t)M * H;        // 8192*226  : final linear out
    float* part = buf3 + (size_t)M * NO;       // 2*32*1024 partials
    float* scale = part + (size_t)2 * NCHUNK * H;
    float* shift = scale + H;
    int*   flag  = (int*)(shift + H);

    dim3 blk(256);
    const int n4 = M * H / 4;

    // dtype detection from W0 (in_sizes[1] elements; scan as uint16 — within
    // the buffer under either dtype interpretation)
    detect_kernel<<<1, blk, 0, stream>>>((const unsigned short*)W0, in_sizes[1], flag);

    auto bnstep = [&](float* Y, const void* g, const void* be, int relu) {
        colstats_kernel<<<dim3(H / 256, NCHUNK), blk, 0, stream>>>(Y, part, H, M / NCHUNK);
        finalize_stats_kernel<<<dim3(H / 256), blk, 0, stream>>>(part, g, be, scale, shift, H, NCHUNK, 1.0f / M, flag);
        bn_apply_kernel<<<dim3(n4 / 256), blk, 0, stream>>>(Y, scale, shift, relu, n4, H);
    };

    // layer 0: h = relu(bn(x @ W0 + b0))
    gemm_kernel<false><<<dim3(H / 64, M / 64), blk, 0, stream>>>(x, W0, b0, buf0, M, H, K0, flag);
    bnstep(buf0, g0, be0, 1);

    // block 1
    gemm_kernel<true><<<dim3(H / 64, M / 64), blk, 0, stream>>>(buf0, W1a, b1a, buf1, M, H, H, flag);
    bnstep(buf1, g1a, be1a, 1);
    gemm_kernel<true><<<dim3(H / 64, M / 64), blk, 0, stream>>>(buf1, W1b, b1b, buf2, M, H, H, flag);
    bnstep(buf2, g1b, be1b, 0);
    resid_relu_kernel<<<dim3(n4 / 256), blk, 0, stream>>>(buf0, buf2, n4);

    // block 2
    gemm_kernel<true><<<dim3(H / 64, M / 64), blk, 0, stream>>>(buf0, W2a, b2a, buf1, M, H, H, flag);
    bnstep(buf1, g2a, be2a, 1);
    gemm_kernel<true><<<dim3(H / 64, M / 64), blk, 0, stream>>>(buf1, W2b, b2b, buf2, M, H, H, flag);
    bnstep(buf2, g2b, be2b, 0);
    resid_relu_kernel<<<dim3(n4 / 256), blk, 0, stream>>>(buf0, buf2, n4);

    // final linear
    gemm_kernel<true><<<dim3((NO + 63) / 64, M / 64), blk, 0, stream>>>(buf0, W3, b3, buf3, M, NO, H, flag);

    // SVD epilogue -> d_out (rotmat then betas), dtype per flag
    svd_kernel<<<dim3((M * 24 + 255) / 256), blk, 0, stream>>>(buf3, d_out, M, flag);
}

// Round 3
// 3010.164 us; speedup vs baseline: 3.2558x; 3.2558x over previous
//
#include <hip/hip_runtime.h>
#include <hip/hip_bf16.h>
#include <math.h>

typedef __hip_bfloat16 bf16;

__device__ __forceinline__ float bf2f(unsigned short u) {
    unsigned int w = ((unsigned int)u) << 16;
    float f;
    __builtin_memcpy(&f, &w, 4);
    return f;
}

// runtime-flag load (memory-bound kernels only)
__device__ __forceinline__ float ldf(const void* p, size_t i, int f) {
    return f ? ((const float*)p)[i] : bf2f(((const unsigned short*)p)[i]);
}

// compile-time dtype load (hot GEMM path)
template <int DT>
__device__ __forceinline__ float ld(const void* p, size_t i) {
    if (DT) return ((const float*)p)[i];
    return bf2f(((const unsigned short*)p)[i]);
}

template <int DT>
__device__ __forceinline__ float4 ldB4(const void* p, size_t i) {
    if (DT) return *(const float4*)&((const float*)p)[i];
    ushort4 u = *(const ushort4*)&((const unsigned short*)p)[i];
    float4 v;
    v.x = bf2f(u.x); v.y = bf2f(u.y); v.z = bf2f(u.z); v.w = bf2f(u.w);
    return v;
}

// ---------------------------------------------------------------------------
// dtype detector: scan first n uint16s of W0. bf16 N(0,0.02) data: exponent
// field never >= 0xC5. fp32 reinterpreted: low halves quasi-random -> ~23% of
// them hit >= 0xC5 (~3770 expected at n=16384, sigma~54). flag = (cnt>1000).
// ---------------------------------------------------------------------------
__global__ __launch_bounds__(256) void detect_kernel(
    const unsigned short* __restrict__ w, int n, int* __restrict__ flag)
{
    __shared__ int red[256];
    int cnt = 0;
    for (int i = threadIdx.x; i < n; i += 256) {
        unsigned int e = (w[i] >> 7) & 0xFF;
        cnt += (e >= 0xC5) ? 1 : 0;
    }
    red[threadIdx.x] = cnt;
    __syncthreads();
    for (int s = 128; s > 0; s >>= 1) {
        if (threadIdx.x < s) red[threadIdx.x] += red[threadIdx.x + s];
        __syncthreads();
    }
    if (threadIdx.x == 0) flag[0] = (red[0] > 1000) ? 1 : 0;
}

// ---------------------------------------------------------------------------
// repack x [M,Ktrue] (dtype per flag) -> xp [M,Keff] fp32, zero-padded cols.
// ---------------------------------------------------------------------------
__global__ __launch_bounds__(256) void repack_kernel(
    const void* __restrict__ x, float* __restrict__ xp,
    int M, int Ktrue, int Keff, const int* __restrict__ flag)
{
    const int f = flag[0];
    int idx = blockIdx.x * 256 + threadIdx.x;  // one float4 of xp
    int n4 = (M * Keff) >> 2;
    if (idx >= n4) return;
    int row = (idx << 2) / Keff;
    int col = (idx << 2) - row * Keff;
    float4 v;
    float* pv = &v.x;
#pragma unroll
    for (int e = 0; e < 4; e++) {
        int c = col + e;
        pv[e] = (c < Ktrue) ? ldf(x, (size_t)row * Ktrue + c, f) : 0.f;
    }
    ((float4*)xp)[idx] = v;
}

// ---------------------------------------------------------------------------
// Tiled fp32 GEMM: C[M,N] = A[M,Ka(cols)] @ B[Ktrue,N] + bias[N]
// 128x128 tile, BK=16, 256 threads, 8x8 micro-tile.
// DT: input dtype (gates the whole kernel via flag). AVEC: A is fp32 with
// Ka%4==0 rows -> float4 loads; else scalar ld<DT> guarded by kg<Ka.
// NV4: N%4==0 and N%128==0 -> vector B loads / unguarded C stores.
// Loop runs Keff (%16==0) k-steps; B guarded by kg<Ktrue.
// M must be %128.
// ---------------------------------------------------------------------------
template <int DT, bool AVEC, bool NV4>
__global__ __launch_bounds__(256) void gemm128(
    const void* __restrict__ A, const void* __restrict__ B,
    const void* __restrict__ bias, float* __restrict__ C,
    int M, int N, int Keff, int Ktrue, int Ka,
    const int* __restrict__ flag)
{
    if (flag[0] != DT) return;

    __shared__ __align__(16) float As[16][132];
    __shared__ __align__(16) float Bs[16][132];

    const int tid = threadIdx.x;
    const int bm = blockIdx.y * 128;
    const int bn = blockIdx.x * 128;
    const int tx = tid & 15;
    const int ty = tid >> 4;

    const int arow = tid >> 2;   // 0..63 (+64 for second half)
    const int ac   = tid & 3;    // float4 chunk along k
    const int bk   = tid >> 4;   // 0..15 k-row
    const int bc   = tid & 15;   // float4 chunk along n (+16 second)

    float acc[8][8] = {};

    for (int k0 = 0; k0 < Keff; k0 += 16) {
        // ---- stage A (transposed into As[k][m]) ----
        if (AVEC) {
            const float* Af = (const float*)A;
#pragma unroll
            for (int h = 0; h < 2; h++) {
                int r = arow + h * 64;
                float4 v = *(const float4*)&Af[(size_t)(bm + r) * Ka + k0 + ac * 4];
                const float* pv = &v.x;
#pragma unroll
                for (int e = 0; e < 4; e++)
                    As[ac * 4 + e][r] = pv[e];
            }
        } else {
#pragma unroll
            for (int h = 0; h < 2; h++) {
                int r = arow + h * 64;
#pragma unroll
                for (int e = 0; e < 4; e++) {
                    int kg = k0 + ac * 4 + e;
                    As[ac * 4 + e][r] =
                        (kg < Ka) ? ld<DT>(A, (size_t)(bm + r) * Ka + kg) : 0.f;
                }
            }
        }
        // ---- stage B ----
        {
            int kg = k0 + bk;
            bool kok = (kg < Ktrue);
#pragma unroll
            for (int h = 0; h < 2; h++) {
                int cc = bc * 4 + h * 64;
                if (NV4) {
                    float4 v = {0.f, 0.f, 0.f, 0.f};
                    if (kok) v = ldB4<DT>(B, (size_t)kg * N + bn + cc);
                    *(float4*)&Bs[bk][cc] = v;
                } else {
#pragma unroll
                    for (int e = 0; e < 4; e++) {
                        int col = bn + cc + e;
                        Bs[bk][cc + e] =
                            (kok && col < N) ? ld<DT>(B, (size_t)kg * N + col) : 0.f;
                    }
                }
            }
        }
        __syncthreads();

#pragma unroll
        for (int k = 0; k < 16; k++) {
            float4 a0 = *(const float4*)&As[k][ty * 4];
            float4 a1 = *(const float4*)&As[k][ty * 4 + 64];
            float4 b0 = *(const float4*)&Bs[k][tx * 4];
            float4 b1 = *(const float4*)&Bs[k][tx * 4 + 64];
            float av[8] = {a0.x, a0.y, a0.z, a0.w, a1.x, a1.y, a1.z, a1.w};
            float bv[8] = {b0.x, b0.y, b0.z, b0.w, b1.x, b1.y, b1.z, b1.w};
#pragma unroll
            for (int i = 0; i < 8; i++)
#pragma unroll
                for (int j = 0; j < 8; j++)
                    acc[i][j] += av[i] * bv[j];
        }
        __syncthreads();
    }

    // ---- epilogue: bias add + store ----
#pragma unroll
    for (int i = 0; i < 8; i++) {
        int row = bm + (i < 4 ? ty * 4 + i : 64 + ty * 4 + (i - 4));
#pragma unroll
        for (int jh = 0; jh < 2; jh++) {
#pragma unroll
            for (int e = 0; e < 4; e++) {
                int j = jh * 4 + e;
                int col = bn + jh * 64 + tx * 4 + e;
                if (NV4 || col < N)
                    C[(size_t)row * N + col] = acc[i][j] + ld<DT>(bias, col);
            }
        }
    }
}

// ---------------------------------------------------------------------------
__global__ __launch_bounds__(256) void colstats_kernel(
    const float* __restrict__ Y, float* __restrict__ part, int N, int rows)
{
    int c = blockIdx.x * 256 + threadIdx.x;
    int r0 = blockIdx.y * rows;
    const float* p = Y + (size_t)r0 * N + c;
    float s = 0.f, s2 = 0.f;
    for (int r = 0; r < rows; r++) {
        float v = p[(size_t)r * N];
        s += v;
        s2 += v * v;
    }
    part[(size_t)(blockIdx.y * 2 + 0) * N + c] = s;
    part[(size_t)(blockIdx.y * 2 + 1) * N + c] = s2;
}

__global__ void finalize_stats_kernel(
    const float* __restrict__ part, const void* __restrict__ g,
    const void* __restrict__ be, float* __restrict__ scale,
    float* __restrict__ shift, int N, int nchunk, float invM,
    const int* __restrict__ flag)
{
    const int f = flag[0];
    int c = blockIdx.x * blockDim.x + threadIdx.x;
    if (c >= N) return;
    float s = 0.f, s2 = 0.f;
    for (int i = 0; i < nchunk; i++) {
        s  += part[(size_t)(2 * i + 0) * N + c];
        s2 += part[(size_t)(2 * i + 1) * N + c];
    }
    float m = s * invM;
    float v = s2 * invM - m * m;
    if (v < 0.f) v = 0.f;
    float sc = ldf(g, c, f) / sqrtf(v + 1e-5f);
    scale[c] = sc;
    shift[c] = ldf(be, c, f) - m * sc;
}

__global__ __launch_bounds__(256) void bn_apply_kernel(
    float* __restrict__ Y, const float* __restrict__ scale,
    const float* __restrict__ shift, int do_relu, int n4, int N)
{
    int idx = blockIdx.x * 256 + threadIdx.x;
    if (idx >= n4) return;
    float4* Y4 = (float4*)Y;
    float4 v = Y4[idx];
    int c = (idx * 4) & (N - 1);
    v.x = v.x * scale[c + 0] + shift[c + 0];
    v.y = v.y * scale[c + 1] + shift[c + 1];
    v.z = v.z * scale[c + 2] + shift[c + 2];
    v.w = v.w * scale[c + 3] + shift[c + 3];
    if (do_relu) {
        v.x = fmaxf(v.x, 0.f); v.y = fmaxf(v.y, 0.f);
        v.z = fmaxf(v.z, 0.f); v.w = fmaxf(v.w, 0.f);
    }
    Y4[idx] = v;
}

__global__ __launch_bounds__(256) void resid_relu_kernel(
    float* __restrict__ H, const float* __restrict__ T, int n4)
{
    int idx = blockIdx.x * 256 + threadIdx.x;
    if (idx >= n4) return;
    float4 h = ((float4*)H)[idx];
    float4 t = ((const float4*)T)[idx];
    h.x = fmaxf(h.x + t.x, 0.f);
    h.y = fmaxf(h.y + t.y, 0.f);
    h.z = fmaxf(h.z + t.z, 0.f);
    h.w = fmaxf(h.w + t.w, 0.f);
    ((float4*)H)[idx] = h;
}

// ---------------------------------------------------------------------------
// O = det(R)*R, R = polar(M). Jacobi eigensolver on M^T M in fp64.
// Output dtype follows detected input dtype (flag).
// ---------------------------------------------------------------------------
__global__ __launch_bounds__(256) void svd_kernel(
    const float* __restrict__ O3, void* __restrict__ out,
    int nb, const int* __restrict__ flag)
{
    const int f = flag[0];
    int gidx = blockIdx.x * 256 + threadIdx.x;
    if (gidx >= nb * 24) return;
    int row = gidx / 24;
    int j = gidx - row * 24;
    const float* rowp = O3 + (size_t)row * 226;
    const float* src = rowp + j * 9;

    double m[3][3];
#pragma unroll
    for (int r = 0; r < 3; r++)
#pragma unroll
        for (int c = 0; c < 3; c++) m[r][c] = (double)src[r * 3 + c];

    double a[3][3];
#pragma unroll
    for (int r = 0; r < 3; r++)
#pragma unroll
        for (int c = 0; c < 3; c++) {
            double s = 0.0;
#pragma unroll
            for (int k = 0; k < 3; k++) s += m[k][r] * m[k][c];
            a[r][c] = s;
        }

    double V[3][3] = {{1, 0, 0}, {0, 1, 0}, {0, 0, 1}};
    const int PP[3] = {0, 0, 1}, QQ[3] = {1, 2, 2};
    for (int sweep = 0; sweep < 8; sweep++) {
        for (int r3 = 0; r3 < 3; r3++) {
            int p = PP[r3], q = QQ[r3];
            double apq = a[p][q];
            if (fabs(apq) < 1e-60) continue;
            double tau = (a[q][q] - a[p][p]) / (2.0 * apq);
            double t = ((tau >= 0.0) ? 1.0 : -1.0) / (fabs(tau) + sqrt(1.0 + tau * tau));
            double c = 1.0 / sqrt(1.0 + t * t);
            double s = t * c;
#pragma unroll
            for (int k = 0; k < 3; k++) {
                double xp = a[p][k], xq = a[q][k];
                a[p][k] = c * xp - s * xq;
                a[q][k] = s * xp + c * xq;
            }
#pragma unroll
            for (int k = 0; k < 3; k++) {
                double xp = a[k][p], xq = a[k][q];
                a[k][p] = c * xp - s * xq;
                a[k][q] = s * xp + c * xq;
            }
#pragma unroll
            for (int k = 0; k < 3; k++) {
                double xp = V[k][p], xq = V[k][q];
                V[k][p] = c * xp - s * xq;
                V[k][q] = s * xp + c * xq;
            }
        }
    }

    double lam[3] = {a[0][0], a[1][1], a[2][2]};
    int i3 = 0;
    if (lam[1] < lam[i3]) i3 = 1;
    if (lam[2] < lam[i3]) i3 = 2;
    int i1 = (i3 + 1) % 3, i2 = (i3 + 2) % 3;

    double v1[3], v2[3], v3[3];
#pragma unroll
    for (int k = 0; k < 3; k++) {
        v1[k] = V[k][i1];
        v2[k] = V[k][i2];
        v3[k] = V[k][i3];
    }

    double u1[3], u2[3];
#pragma unroll
    for (int r = 0; r < 3; r++)
        u1[r] = m[r][0] * v1[0] + m[r][1] * v1[1] + m[r][2] * v1[2];
    double n1 = sqrt(u1[0] * u1[0] + u1[1] * u1[1] + u1[2] * u1[2]);
    double inv1 = (n1 > 1e-150) ? 1.0 / n1 : 0.0;
#pragma unroll
    for (int r = 0; r < 3; r++) u1[r] *= inv1;

#pragma unroll
    for (int r = 0; r < 3; r++)
        u2[r] = m[r][0] * v2[0] + m[r][1] * v2[1] + m[r][2] * v2[2];
    double d12 = u1[0] * u2[0] + u1[1] * u2[1] + u1[2] * u2[2];
#pragma unroll
    for (int r = 0; r < 3; r++) u2[r] -= d12 * u1[r];
    double n2 = sqrt(u2[0] * u2[0] + u2[1] * u2[1] + u2[2] * u2[2]);
    double inv2 = (n2 > 1e-150) ? 1.0 / n2 : 0.0;
#pragma unroll
    for (int r = 0; r < 3; r++) u2[r] *= inv2;

    double detM = m[0][0] * (m[1][1] * m[2][2] - m[1][2] * m[2][1])
                - m[0][1] * (m[1][0] * m[2][2] - m[1][2] * m[2][0])
                + m[0][2] * (m[1][0] * m[2][1] - m[1][1] * m[2][0]);
    double sgn = (detM >= 0.0) ? 1.0 : -1.0;
    double detV = v1[0] * (v2[1] * v3[2] - v2[2] * v3[1])
                - v1[1] * (v2[0] * v3[2] - v2[2] * v3[0])
                + v1[2] * (v2[0] * v3[1] - v2[1] * v3[0]);
    double sv = (detV >= 0.0) ? 1.0 : -1.0;

    double u3[3];
    u3[0] = sgn * sv * (u1[1] * u2[2] - u1[2] * u2[1]);
    u3[1] = sgn * sv * (u1[2] * u2[0] - u1[0] * u2[2]);
    u3[2] = sgn * sv * (u1[0] * u2[1] - u1[1] * u2[0]);

    size_t rot_base = (size_t)gidx * 9;
    size_t beta_base = (size_t)nb * 24 * 9 + (size_t)row * 10;
#pragma unroll
    for (int r = 0; r < 3; r++)
#pragma unroll
        for (int c = 0; c < 3; c++) {
            float o = (float)(sgn * (u1[r] * v1[c] + u2[r] * v2[c] + u3[r] * v3[c]));
            if (f) ((float*)out)[rot_base + r * 3 + c] = o;
            else   ((bf16*)out)[rot_base + r * 3 + c] = __float2bfloat16(o);
        }

    if (j < 10) {
        float b = rowp[216 + j];
        if (f) ((float*)out)[beta_base + j] = b;
        else   ((bf16*)out)[beta_base + j] = __float2bfloat16(b);
    }
}

// ---------------------------------------------------------------------------
extern "C" void kernel_launch(void* const* d_in, const int* in_sizes, int n_in,
                              void* d_out, int out_size, void* d_ws, size_t ws_size,
                              hipStream_t stream)
{
    const void* x    = d_in[0];
    const void* W0   = d_in[1];
    const void* b0   = d_in[2];
    const void* g0   = d_in[3];
    const void* be0  = d_in[4];
    const void* W1a  = d_in[5];
    const void* b1a  = d_in[6];
    const void* g1a  = d_in[7];
    const void* be1a = d_in[8];
    const void* W1b  = d_in[9];
    const void* b1b  = d_in[10];
    const void* g1b  = d_in[11];
    const void* be1b = d_in[12];
    const void* W2a  = d_in[13];
    const void* b2a  = d_in[14];
    const void* g2a  = d_in[15];
    const void* be2a = d_in[16];
    const void* W2b  = d_in[17];
    const void* b2b  = d_in[18];
    const void* g2b  = d_in[19];
    const void* be2b = d_in[20];
    const void* W3   = d_in[21];
    const void* b3   = d_in[22];

    const int M = 8192, H = 1024, K0 = 5169, K0P = 5184, NO = 226;
    const int NCHUNK = 32;

    const size_t SZ_ACT = (size_t)M * H;          // 8388608 floats
    const size_t SZ_XP  = (size_t)M * K0P;        // 42467328 floats
    const size_t SZ_O3  = (size_t)M * NO;
    const size_t SZ_PART = (size_t)2 * NCHUNK * H;

    float* ws = (float*)d_ws;
    float* buf0 = ws;

    // Can we afford the padded-x repack region?
    size_t need_repack = (SZ_ACT + SZ_XP + 2 * H + 16) * 4;
    bool use_repack = ws_size >= need_repack;

    float *xp, *buf1, *buf2, *buf3, *part, *scale;
    if (use_repack) {
        xp   = buf0 + SZ_ACT;
        buf1 = xp;                 // xp dead after GEMM0
        buf2 = buf1 + SZ_ACT;
        buf3 = buf2 + SZ_ACT;
        part = buf3 + SZ_O3;
        scale = xp + SZ_XP;
    } else {
        xp   = nullptr;
        buf1 = buf0 + SZ_ACT;
        buf2 = buf1 + SZ_ACT;
        buf3 = buf2 + SZ_ACT;
        part = buf3 + SZ_O3;
        scale = part + SZ_PART;
    }
    float* shift = scale + H;
    int*   flag  = (int*)(shift + H);

    dim3 blk(256);
    const int n4 = M * H / 4;

    // 1. dtype detection (16K uint16s is >50 sigma separation)
    int nscan = in_sizes[1] < 16384 ? in_sizes[1] : 16384;
    detect_kernel<<<1, blk, 0, stream>>>((const unsigned short*)W0, nscan, flag);

    auto bnstep = [&](float* Y, const void* g, const void* be, int relu) {
        colstats_kernel<<<dim3(H / 256, NCHUNK), blk, 0, stream>>>(Y, part, H, M / NCHUNK);
        finalize_stats_kernel<<<dim3(H / 256), blk, 0, stream>>>(part, g, be, scale, shift, H, NCHUNK, 1.0f / M, flag);
        bn_apply_kernel<<<dim3(n4 / 256), blk, 0, stream>>>(Y, scale, shift, relu, n4, H);
    };

    // Launch both dtype specializations; each gates on flag.
    auto gemmA = [&](const float* A, const void* B, const void* bias, float* C,
                     int N, int Keff, int Ktrue, int Ka, bool nv4) {
        dim3 grid((N + 127) / 128, M / 128);
        if (nv4) {
            gemm128<1, true, true><<<grid, blk, 0, stream>>>(A, B, bias, C, M, N, Keff, Ktrue, Ka, flag);
            gemm128<0, true, true><<<grid, blk, 0, stream>>>(A, B, bias, C, M, N, Keff, Ktrue, Ka, flag);
        } else {
            gemm128<1, true, false><<<grid, blk, 0, stream>>>(A, B, bias, C, M, N, Keff, Ktrue, Ka, flag);
            gemm128<0, true, false><<<grid, blk, 0, stream>>>(A, B, bias, C, M, N, Keff, Ktrue, Ka, flag);
        }
    };

    // 2. layer 0: h = relu(bn(x @ W0 + b0))
    if (use_repack) {
        int rblocks = (int)((SZ_XP / 4 + 255) / 256);
        repack_kernel<<<dim3(rblocks), blk, 0, stream>>>(x, xp, M, K0, K0P, flag);
        gemmA(xp, W0, b0, buf0, H, K0P, K0, K0P, true);
    } else {
        dim3 grid(H / 128, M / 128);
        gemm128<1, false, true><<<grid, blk, 0, stream>>>(x, W0, b0, buf0, M, H, K0P, K0, K0, flag);
        gemm128<0, false, true><<<grid, blk, 0, stream>>>(x, W0, b0, buf0, M, H, K0P, K0, K0, flag);
    }
    bnstep(buf0, g0, be0, 1);

    // 3. block 1
    gemmA(buf0, W1a, b1a, buf1, H, H, H, H, true);
    bnstep(buf1, g1a, be1a, 1);
    gemmA(buf1, W1b, b1b, buf2, H, H, H, H, true);
    bnstep(buf2, g1b, be1b, 0);
    resid_relu_kernel<<<dim3(n4 / 256), blk, 0, stream>>>(buf0, buf2, n4);

    // 4. block 2
    gemmA(buf0, W2a, b2a, buf1, H, H, H, H, true);
    bnstep(buf1, g2a, be2a, 1);
    gemmA(buf1, W2b, b2b, buf2, H, H, H, H, true);
    bnstep(buf2, g2b, be2b, 0);
    resid_relu_kernel<<<dim3(n4 / 256), blk, 0, stream>>>(buf0, buf2, n4);

    // 5. final linear
    gemmA(buf0, W3, b3, buf3, NO, H, H, H, false);

    // 6. SVD epilogue -> d_out (rotmat then betas), dtype per flag
    svd_kernel<<<dim3((M * 24 + 255) / 256), blk, 0, stream>>>(buf3, d_out, M, flag);
}

// Round 4
// 2085.316 us; speedup vs baseline: 4.6997x; 1.4435x over previous
//
#include <hip/hip_runtime.h>
#include <hip/hip_bf16.h>
#include <math.h>

typedef __hip_bfloat16 bf16;
typedef __attribute__((ext_vector_type(8))) short short8;
typedef __attribute__((ext_vector_type(4))) float floatx4;

__device__ __forceinline__ float bfu2f(unsigned short u) {
    unsigned int w = ((unsigned int)u) << 16;
    float f;
    __builtin_memcpy(&f, &w, 4);
    return f;
}
__device__ __forceinline__ unsigned short f2bfu(float x) {
    bf16 b = __float2bfloat16(x);  // RNE
    unsigned short u;
    __builtin_memcpy(&u, &b, 2);
    return u;
}
// exact 3-way split: a = s0+s1+s2 + err, |err| <= 2^-27 |a|
__device__ __forceinline__ void split3(float a, unsigned short& s0,
                                       unsigned short& s1, unsigned short& s2) {
    s0 = f2bfu(a);
    float r1 = a - bfu2f(s0);   // exact (Sterbenz)
    s1 = f2bfu(r1);
    float r2 = r1 - bfu2f(s1);  // exact
    s2 = f2bfu(r2);
}

// ---------------------------------------------------------------------------
// Weight transpose + 3-way bf16 split: W[Ktrue,N] fp32 -> 3 planes [N][Kpad]
// bf16, zero-filled for k in [Ktrue,Kpad).
// ---------------------------------------------------------------------------
__global__ __launch_bounds__(256) void wsplit_kernel(
    const float* __restrict__ W, unsigned short* __restrict__ out,
    int Ktrue, int Kpad, int N)
{
    __shared__ float T[32][33];
    const int tx = threadIdx.x & 31, ty = threadIdx.x >> 5;
    const int k0 = blockIdx.x * 32, n0 = blockIdx.y * 32;
#pragma unroll
    for (int i = 0; i < 4; i++) {
        int k = k0 + ty + 8 * i, n = n0 + tx;
        T[ty + 8 * i][tx] = (k < Ktrue && n < N) ? W[(size_t)k * N + n] : 0.f;
    }
    __syncthreads();
    const size_t PS = (size_t)N * Kpad;
#pragma unroll
    for (int i = 0; i < 4; i++) {
        int n = n0 + ty + 8 * i, k = k0 + tx;
        if (n < N) {
            unsigned short h0, h1, h2;
            split3(T[tx][ty + 8 * i], h0, h1, h2);
            size_t base = (size_t)n * Kpad + k;
            out[0 * PS + base] = h0;
            out[1 * PS + base] = h1;
            out[2 * PS + base] = h2;
        }
    }
}

// ---------------------------------------------------------------------------
// Fused 6-product split-bf16 MFMA GEMM (fp32-equivalent):
//   C[M,N] = A[M,Ka] @ W[.,N] + bias,  W pre-split as 3 bf16 planes [N][Kpad].
// 128x128 tile, BK=32, 256 thr (4 waves), per wave 4x4 of 16x16x32 MFMA,
// 6 products (pa+pb<=2) into one fp32 accumulator.
// AVEC: A fp32 with 16B-alignable rows (Ka%4==0). NG: guard N (W3).
// ---------------------------------------------------------------------------
template <bool AVEC, bool NG>
__global__ __launch_bounds__(256) void mfma_gemm(
    const float* __restrict__ A, const unsigned short* __restrict__ Bpl,
    const float* __restrict__ bias, float* __restrict__ C,
    int M, int N, int Kpad, int Ka)
{
    __shared__ __align__(16) short As[3][128][40];
    __shared__ __align__(16) short Bs[3][128][40];

    const int tid = threadIdx.x;
    const int lane = tid & 63;
    const int wave = tid >> 6;
    const int wm = (wave & 1) * 64, wn = (wave >> 1) * 64;
    const int bm = blockIdx.y * 128, bn = blockIdx.x * 128;
    const int r = tid >> 1;          // 0..127 (row of A-tile / n-row of B-tile)
    const int half = tid & 1;        // 16-element half along k
    const int l15 = lane & 15, q = lane >> 4;
    const size_t PS = (size_t)N * Kpad;

    floatx4 acc[4][4] = {};

    for (int k0 = 0; k0 < Kpad; k0 += 32) {
        // ---- stage A: 16 fp32 -> 3 bf16 planes ----
        {
            float v[16];
            if (AVEC) {
                const float* Ap = A + (size_t)(bm + r) * Ka + k0 + half * 16;
#pragma unroll
                for (int qq = 0; qq < 4; qq++) {
                    float4 f = ((const float4*)Ap)[qq];
                    v[qq * 4 + 0] = f.x; v[qq * 4 + 1] = f.y;
                    v[qq * 4 + 2] = f.z; v[qq * 4 + 3] = f.w;
                }
            } else {
#pragma unroll
                for (int e = 0; e < 16; e++) {
                    int kg = k0 + half * 16 + e;
                    v[e] = (kg < Ka) ? A[(size_t)(bm + r) * Ka + kg] : 0.f;
                }
            }
            unsigned short s[3][16];
#pragma unroll
            for (int e = 0; e < 16; e++)
                split3(v[e], s[0][e], s[1][e], s[2][e]);
#pragma unroll
            for (int p = 0; p < 3; p++) {
                *(short8*)&As[p][r][half * 16]     = *(short8*)&s[p][0];
                *(short8*)&As[p][r][half * 16 + 8] = *(short8*)&s[p][8];
            }
        }
        // ---- stage B: copy pre-split planes ----
        {
            int n = bn + r;
            short8 z = {0, 0, 0, 0, 0, 0, 0, 0};
#pragma unroll
            for (int p = 0; p < 3; p++) {
                short8 b0 = z, b1 = z;
                if (!NG || n < N) {
                    const unsigned short* bp =
                        Bpl + (size_t)p * PS + (size_t)n * Kpad + k0 + half * 16;
                    b0 = *(const short8*)bp;
                    b1 = *(const short8*)(bp + 8);
                }
                *(short8*)&Bs[p][r][half * 16]     = b0;
                *(short8*)&Bs[p][r][half * 16 + 8] = b1;
            }
        }
        __syncthreads();

        // ---- compute: 6 products, shared accumulator ----
        short8 bfr[3][4];
#pragma unroll
        for (int p = 0; p < 3; p++)
#pragma unroll
            for (int ni = 0; ni < 4; ni++)
                bfr[p][ni] = *(short8*)&Bs[p][wn + ni * 16 + l15][q * 8];
#pragma unroll
        for (int pa = 0; pa < 3; pa++) {
            short8 af[4];
#pragma unroll
            for (int mi = 0; mi < 4; mi++)
                af[mi] = *(short8*)&As[pa][wm + mi * 16 + l15][q * 8];
#pragma unroll
            for (int pb = 0; pb < 3; pb++) {
                if (pa + pb > 2) continue;
#pragma unroll
                for (int mi = 0; mi < 4; mi++)
#pragma unroll
                    for (int ni = 0; ni < 4; ni++)
                        acc[mi][ni] = __builtin_amdgcn_mfma_f32_16x16x32_bf16(
                            af[mi], bfr[pb][ni], acc[mi][ni], 0, 0, 0);
            }
        }
        __syncthreads();
    }

    // ---- epilogue: bias + store (C/D layout: col=lane&15, row=q*4+reg) ----
#pragma unroll
    for (int ni = 0; ni < 4; ni++) {
        int col = bn + wn + ni * 16 + l15;
        if (NG && col >= N) continue;
        float bv = bias[col];
#pragma unroll
        for (int mi = 0; mi < 4; mi++) {
#pragma unroll
            for (int reg = 0; reg < 4; reg++) {
                int row = bm + wm + mi * 16 + q * 4 + reg;
                C[(size_t)row * N + col] = acc[mi][ni][reg] + bv;
            }
        }
    }
}

// ---------------------------------------------------------------------------
// fp32 fallback GEMM (round-3 proven), used only if ws too small for planes.
// ---------------------------------------------------------------------------
template <bool AVEC, bool NV4>
__global__ __launch_bounds__(256) void gemm128(
    const float* __restrict__ A, const float* __restrict__ B,
    const float* __restrict__ bias, float* __restrict__ C,
    int M, int N, int Keff, int Ktrue, int Ka)
{
    __shared__ __align__(16) float Asm[16][132];
    __shared__ __align__(16) float Bsm[16][132];
    const int tid = threadIdx.x;
    const int bm = blockIdx.y * 128, bn = blockIdx.x * 128;
    const int tx = tid & 15, ty = tid >> 4;
    const int arow = tid >> 2, ac = tid & 3;
    const int bk = tid >> 4, bc = tid & 15;
    float acc[8][8] = {};
    for (int k0 = 0; k0 < Keff; k0 += 16) {
#pragma unroll
        for (int h = 0; h < 2; h++) {
            int rr = arow + h * 64;
            if (AVEC) {
                float4 v = *(const float4*)&A[(size_t)(bm + rr) * Ka + k0 + ac * 4];
                const float* pv = &v.x;
#pragma unroll
                for (int e = 0; e < 4; e++) Asm[ac * 4 + e][rr] = pv[e];
            } else {
#pragma unroll
                for (int e = 0; e < 4; e++) {
                    int kg = k0 + ac * 4 + e;
                    Asm[ac * 4 + e][rr] = (kg < Ka) ? A[(size_t)(bm + rr) * Ka + kg] : 0.f;
                }
            }
        }
        {
            int kg = k0 + bk;
            bool kok = (kg < Ktrue);
#pragma unroll
            for (int h = 0; h < 2; h++) {
                int cc = bc * 4 + h * 64;
                if (NV4) {
                    float4 v = {0.f, 0.f, 0.f, 0.f};
                    if (kok) v = *(const float4*)&B[(size_t)kg * N + bn + cc];
                    *(float4*)&Bsm[bk][cc] = v;
                } else {
#pragma unroll
                    for (int e = 0; e < 4; e++) {
                        int col = bn + cc + e;
                        Bsm[bk][cc + e] = (kok && col < N) ? B[(size_t)kg * N + col] : 0.f;
                    }
                }
            }
        }
        __syncthreads();
#pragma unroll
        for (int k = 0; k < 16; k++) {
            float4 a0 = *(const float4*)&Asm[k][ty * 4];
            float4 a1 = *(const float4*)&Asm[k][ty * 4 + 64];
            float4 b0 = *(const float4*)&Bsm[k][tx * 4];
            float4 b1 = *(const float4*)&Bsm[k][tx * 4 + 64];
            float av[8] = {a0.x, a0.y, a0.z, a0.w, a1.x, a1.y, a1.z, a1.w};
            float bv[8] = {b0.x, b0.y, b0.z, b0.w, b1.x, b1.y, b1.z, b1.w};
#pragma unroll
            for (int i = 0; i < 8; i++)
#pragma unroll
                for (int j = 0; j < 8; j++) acc[i][j] += av[i] * bv[j];
        }
        __syncthreads();
    }
#pragma unroll
    for (int i = 0; i < 8; i++) {
        int row = bm + (i < 4 ? ty * 4 + i : 64 + ty * 4 + (i - 4));
#pragma unroll
        for (int jh = 0; jh < 2; jh++)
#pragma unroll
            for (int e = 0; e < 4; e++) {
                int col = bn + jh * 64 + tx * 4 + e;
                if (NV4 || col < N)
                    C[(size_t)row * N + col] = acc[i][jh * 4 + e] + bias[col];
            }
    }
}

// ---------------------------------------------------------------------------
__global__ __launch_bounds__(256) void colstats_kernel(
    const float* __restrict__ Y, float* __restrict__ part, int N, int rows)
{
    int c = blockIdx.x * 256 + threadIdx.x;
    int r0 = blockIdx.y * rows;
    const float* p = Y + (size_t)r0 * N + c;
    float s = 0.f, s2 = 0.f;
    for (int r = 0; r < rows; r++) {
        float v = p[(size_t)r * N];
        s += v;
        s2 += v * v;
    }
    part[(size_t)(blockIdx.y * 2 + 0) * N + c] = s;
    part[(size_t)(blockIdx.y * 2 + 1) * N + c] = s2;
}

__global__ void finalize_stats_kernel(
    const float* __restrict__ part, const float* __restrict__ g,
    const float* __restrict__ be, float* __restrict__ scale,
    float* __restrict__ shift, int N, int nchunk, float invM)
{
    int c = blockIdx.x * blockDim.x + threadIdx.x;
    if (c >= N) return;
    float s = 0.f, s2 = 0.f;
    for (int i = 0; i < nchunk; i++) {
        s  += part[(size_t)(2 * i + 0) * N + c];
        s2 += part[(size_t)(2 * i + 1) * N + c];
    }
    float m = s * invM;
    float v = s2 * invM - m * m;
    if (v < 0.f) v = 0.f;
    float sc = g[c] / sqrtf(v + 1e-5f);
    scale[c] = sc;
    shift[c] = be[c] - m * sc;
}

__global__ __launch_bounds__(256) void bn_apply_kernel(
    float* __restrict__ Y, const float* __restrict__ scale,
    const float* __restrict__ shift, int do_relu, int n4, int N)
{
    int idx = blockIdx.x * 256 + threadIdx.x;
    if (idx >= n4) return;
    float4* Y4 = (float4*)Y;
    float4 v = Y4[idx];
    int c = (idx * 4) & (N - 1);
    v.x = v.x * scale[c + 0] + shift[c + 0];
    v.y = v.y * scale[c + 1] + shift[c + 1];
    v.z = v.z * scale[c + 2] + shift[c + 2];
    v.w = v.w * scale[c + 3] + shift[c + 3];
    if (do_relu) {
        v.x = fmaxf(v.x, 0.f); v.y = fmaxf(v.y, 0.f);
        v.z = fmaxf(v.z, 0.f); v.w = fmaxf(v.w, 0.f);
    }
    Y4[idx] = v;
}

__global__ __launch_bounds__(256) void resid_relu_kernel(
    float* __restrict__ H, const float* __restrict__ T, int n4)
{
    int idx = blockIdx.x * 256 + threadIdx.x;
    if (idx >= n4) return;
    float4 h = ((float4*)H)[idx];
    float4 t = ((const float4*)T)[idx];
    h.x = fmaxf(h.x + t.x, 0.f);
    h.y = fmaxf(h.y + t.y, 0.f);
    h.z = fmaxf(h.z + t.z, 0.f);
    h.w = fmaxf(h.w + t.w, 0.f);
    ((float4*)H)[idx] = h;
}

// ---------------------------------------------------------------------------
// O = det(R)*R, R = polar(M). Jacobi on M^T M in fp64. fp32 output.
// ---------------------------------------------------------------------------
__global__ __launch_bounds__(256) void svd_kernel(
    const float* __restrict__ O3, float* __restrict__ out, int nb)
{
    int gidx = blockIdx.x * 256 + threadIdx.x;
    if (gidx >= nb * 24) return;
    int row = gidx / 24;
    int j = gidx - row * 24;
    const float* rowp = O3 + (size_t)row * 226;
    const float* src = rowp + j * 9;

    double m[3][3];
#pragma unroll
    for (int r = 0; r < 3; r++)
#pragma unroll
        for (int c = 0; c < 3; c++) m[r][c] = (double)src[r * 3 + c];

    double a[3][3];
#pragma unroll
    for (int r = 0; r < 3; r++)
#pragma unroll
        for (int c = 0; c < 3; c++) {
            double s = 0.0;
#pragma unroll
            for (int k = 0; k < 3; k++) s += m[k][r] * m[k][c];
            a[r][c] = s;
        }

    double V[3][3] = {{1, 0, 0}, {0, 1, 0}, {0, 0, 1}};
    const int PP[3] = {0, 0, 1}, QQ[3] = {1, 2, 2};
    for (int sweep = 0; sweep < 8; sweep++) {
        for (int r3 = 0; r3 < 3; r3++) {
            int p = PP[r3], q = QQ[r3];
            double apq = a[p][q];
            if (fabs(apq) < 1e-60) continue;
            double tau = (a[q][q] - a[p][p]) / (2.0 * apq);
            double t = ((tau >= 0.0) ? 1.0 : -1.0) / (fabs(tau) + sqrt(1.0 + tau * tau));
            double c = 1.0 / sqrt(1.0 + t * t);
            double s = t * c;
#pragma unroll
            for (int k = 0; k < 3; k++) {
                double xp = a[p][k], xq = a[q][k];
                a[p][k] = c * xp - s * xq;
                a[q][k] = s * xp + c * xq;
            }
#pragma unroll
            for (int k = 0; k < 3; k++) {
                double xp = a[k][p], xq = a[k][q];
                a[k][p] = c * xp - s * xq;
                a[k][q] = s * xp + c * xq;
            }
#pragma unroll
            for (int k = 0; k < 3; k++) {
                double xp = V[k][p], xq = V[k][q];
                V[k][p] = c * xp - s * xq;
                V[k][q] = s * xp + c * xq;
            }
        }
    }

    double lam[3] = {a[0][0], a[1][1], a[2][2]};
    int i3 = 0;
    if (lam[1] < lam[i3]) i3 = 1;
    if (lam[2] < lam[i3]) i3 = 2;
    int i1 = (i3 + 1) % 3, i2 = (i3 + 2) % 3;

    double v1[3], v2[3], v3[3];
#pragma unroll
    for (int k = 0; k < 3; k++) {
        v1[k] = V[k][i1];
        v2[k] = V[k][i2];
        v3[k] = V[k][i3];
    }

    double u1[3], u2[3];
#pragma unroll
    for (int r = 0; r < 3; r++)
        u1[r] = m[r][0] * v1[0] + m[r][1] * v1[1] + m[r][2] * v1[2];
    double n1 = sqrt(u1[0] * u1[0] + u1[1] * u1[1] + u1[2] * u1[2]);
    double inv1 = (n1 > 1e-150) ? 1.0 / n1 : 0.0;
#pragma unroll
    for (int r = 0; r < 3; r++) u1[r] *= inv1;

#pragma unroll
    for (int r = 0; r < 3; r++)
        u2[r] = m[r][0] * v2[0] + m[r][1] * v2[1] + m[r][2] * v2[2];
    double d12 = u1[0] * u2[0] + u1[1] * u2[1] + u1[2] * u2[2];
#pragma unroll
    for (int r = 0; r < 3; r++) u2[r] -= d12 * u1[r];
    double n2 = sqrt(u2[0] * u2[0] + u2[1] * u2[1] + u2[2] * u2[2]);
    double inv2 = (n2 > 1e-150) ? 1.0 / n2 : 0.0;
#pragma unroll
    for (int r = 0; r < 3; r++) u2[r] *= inv2;

    double detM = m[0][0] * (m[1][1] * m[2][2] - m[1][2] * m[2][1])
                - m[0][1] * (m[1][0] * m[2][2] - m[1][2] * m[2][0])
                + m[0][2] * (m[1][0] * m[2][1] - m[1][1] * m[2][0]);
    double sgn = (detM >= 0.0) ? 1.0 : -1.0;
    double detV = v1[0] * (v2[1] * v3[2] - v2[2] * v3[1])
                - v1[1] * (v2[0] * v3[2] - v2[2] * v3[0])
                + v1[2] * (v2[0] * v3[1] - v2[1] * v3[0]);
    double sv = (detV >= 0.0) ? 1.0 : -1.0;

    double u3[3];
    u3[0] = sgn * sv * (u1[1] * u2[2] - u1[2] * u2[1]);
    u3[1] = sgn * sv * (u1[2] * u2[0] - u1[0] * u2[2]);
    u3[2] = sgn * sv * (u1[0] * u2[1] - u1[1] * u2[0]);

    size_t rot_base = (size_t)gidx * 9;
    size_t beta_base = (size_t)nb * 24 * 9 + (size_t)row * 10;
#pragma unroll
    for (int r = 0; r < 3; r++)
#pragma unroll
        for (int c = 0; c < 3; c++)
            out[rot_base + r * 3 + c] =
                (float)(sgn * (u1[r] * v1[c] + u2[r] * v2[c] + u3[r] * v3[c]));

    if (j < 10) out[beta_base + j] = rowp[216 + j];
}

// ---------------------------------------------------------------------------
extern "C" void kernel_launch(void* const* d_in, const int* in_sizes, int n_in,
                              void* d_out, int out_size, void* d_ws, size_t ws_size,
                              hipStream_t stream)
{
    const float* x    = (const float*)d_in[0];
    const float* W0   = (const float*)d_in[1];
    const float* b0   = (const float*)d_in[2];
    const float* g0   = (const float*)d_in[3];
    const float* be0  = (const float*)d_in[4];
    const float* W1a  = (const float*)d_in[5];
    const float* b1a  = (const float*)d_in[6];
    const float* g1a  = (const float*)d_in[7];
    const float* be1a = (const float*)d_in[8];
    const float* W1b  = (const float*)d_in[9];
    const float* b1b  = (const float*)d_in[10];
    const float* g1b  = (const float*)d_in[11];
    const float* be1b = (const float*)d_in[12];
    const float* W2a  = (const float*)d_in[13];
    const float* b2a  = (const float*)d_in[14];
    const float* g2a  = (const float*)d_in[15];
    const float* be2a = (const float*)d_in[16];
    const float* W2b  = (const float*)d_in[17];
    const float* b2b  = (const float*)d_in[18];
    const float* g2b  = (const float*)d_in[19];
    const float* be2b = (const float*)d_in[20];
    const float* W3   = (const float*)d_in[21];
    const float* b3   = (const float*)d_in[22];

    const int M = 8192, H = 1024, K0 = 5169, K0P = 5184, NO = 226;
    const int NCHUNK = 32;

    const size_t SZ_ACT  = (size_t)M * H;
    const size_t SZ_O3   = (size_t)M * NO;
    const size_t SZ_PART = (size_t)2 * NCHUNK * H;

    float* ws   = (float*)d_ws;
    float* buf0 = ws;
    float* buf1 = buf0 + SZ_ACT;
    float* buf2 = buf1 + SZ_ACT;
    float* buf3 = buf2 + SZ_ACT;
    float* part = buf3 + SZ_O3;
    float* scale = part + SZ_PART;
    float* shift = scale + H;
    size_t float_base = 3 * SZ_ACT + SZ_O3 + SZ_PART + 2 * H + 16;

    // bf16 weight planes (3 per weight), [N][Kpad]
    unsigned short* pl = (unsigned short*)(ws + float_base);
    unsigned short* w0p  = pl;
    unsigned short* w1ap = w0p  + (size_t)3 * H * K0P;
    unsigned short* w1bp = w1ap + (size_t)3 * H * H;
    unsigned short* w2ap = w1bp + (size_t)3 * H * H;
    unsigned short* w2bp = w2ap + (size_t)3 * H * H;
    unsigned short* w3p  = w2bp + (size_t)3 * H * H;
    size_t total_bytes = float_base * 4 +
        ((size_t)3 * H * K0P + (size_t)4 * 3 * H * H + (size_t)3 * NO * H) * 2;
    bool use_mfma = ws_size >= total_bytes;

    dim3 blk(256);
    const int n4 = M * H / 4;

    auto bnstep = [&](float* Y, const float* g, const float* be, int relu) {
        colstats_kernel<<<dim3(H / 256, NCHUNK), blk, 0, stream>>>(Y, part, H, M / NCHUNK);
        finalize_stats_kernel<<<dim3(H / 256), blk, 0, stream>>>(part, g, be, scale, shift, H, NCHUNK, 1.0f / M);
        bn_apply_kernel<<<dim3(n4 / 256), blk, 0, stream>>>(Y, scale, shift, relu, n4, H);
    };

    if (use_mfma) {
        // 1. pre-transpose + split weights to bf16 planes
        wsplit_kernel<<<dim3(K0P / 32, H / 32), blk, 0, stream>>>(W0, w0p, K0, K0P, H);
        wsplit_kernel<<<dim3(H / 32, H / 32), blk, 0, stream>>>(W1a, w1ap, H, H, H);
        wsplit_kernel<<<dim3(H / 32, H / 32), blk, 0, stream>>>(W1b, w1bp, H, H, H);
        wsplit_kernel<<<dim3(H / 32, H / 32), blk, 0, stream>>>(W2a, w2ap, H, H, H);
        wsplit_kernel<<<dim3(H / 32, H / 32), blk, 0, stream>>>(W2b, w2bp, H, H, H);
        wsplit_kernel<<<dim3(H / 32, (NO + 31) / 32), blk, 0, stream>>>(W3, w3p, H, H, NO);

        dim3 gH(H / 128, M / 128);
        dim3 gO((NO + 127) / 128, M / 128);

        // 2. layer 0
        mfma_gemm<false, false><<<gH, blk, 0, stream>>>(x, w0p, b0, buf0, M, H, K0P, K0);
        bnstep(buf0, g0, be0, 1);
        // 3. block 1
        mfma_gemm<true, false><<<gH, blk, 0, stream>>>(buf0, w1ap, b1a, buf1, M, H, H, H);
        bnstep(buf1, g1a, be1a, 1);
        mfma_gemm<true, false><<<gH, blk, 0, stream>>>(buf1, w1bp, b1b, buf2, M, H, H, H);
        bnstep(buf2, g1b, be1b, 0);
        resid_relu_kernel<<<dim3(n4 / 256), blk, 0, stream>>>(buf0, buf2, n4);
        // 4. block 2
        mfma_gemm<true, false><<<gH, blk, 0, stream>>>(buf0, w2ap, b2a, buf1, M, H, H, H);
        bnstep(buf1, g2a, be2a, 1);
        mfma_gemm<true, false><<<gH, blk, 0, stream>>>(buf1, w2bp, b2b, buf2, M, H, H, H);
        bnstep(buf2, g2b, be2b, 0);
        resid_relu_kernel<<<dim3(n4 / 256), blk, 0, stream>>>(buf0, buf2, n4);
        // 5. final linear
        mfma_gemm<true, true><<<gO, blk, 0, stream>>>(buf0, w3p, b3, buf3, M, NO, H, H);
    } else {
        // fp32 fallback (round-3 path, no repack)
        dim3 gH(H / 128, M / 128);
        dim3 gO((NO + 127) / 128, M / 128);
        gemm128<false, true><<<gH, blk, 0, stream>>>(x, W0, b0, buf0, M, H, K0P, K0, K0);
        bnstep(buf0, g0, be0, 1);
        gemm128<true, true><<<gH, blk, 0, stream>>>(buf0, W1a, b1a, buf1, M, H, H, H, H);
        bnstep(buf1, g1a, be1a, 1);
        gemm128<true, true><<<gH, blk, 0, stream>>>(buf1, W1b, b1b, buf2, M, H, H, H, H);
        bnstep(buf2, g1b, be1b, 0);
        resid_relu_kernel<<<dim3(n4 / 256), blk, 0, stream>>>(buf0, buf2, n4);
        gemm128<true, true><<<gH, blk, 0, stream>>>(buf0, W2a, b2a, buf1, M, H, H, H, H);
        bnstep(buf1, g2a, be2a, 1);
        gemm128<true, true><<<gH, blk, 0, stream>>>(buf1, W2b, b2b, buf2, M, H, H, H, H);
        bnstep(buf2, g2b, be2b, 0);
        resid_relu_kernel<<<dim3(n4 / 256), blk, 0, stream>>>(buf0, buf2, n4);
        gemm128<true, false><<<gO, blk, 0, stream>>>(buf0, W3, b3, buf3, M, NO, H, H, H);
    }

    // 6. SVD epilogue -> d_out (fp32: rotmat then betas)
    svd_kernel<<<dim3((M * 24 + 255) / 256), blk, 0, stream>>>(buf3, (float*)d_out, M);
}